// Round 7
// baseline (1101.147 us; speedup 1.0000x reference)
//
#include <hip/hip_runtime.h>
#include <hip/hip_bf16.h>
#include <math.h>

typedef __hip_bfloat16 bf16;
typedef unsigned short u16;
typedef unsigned int   u32;
typedef __bf16  bf16x8 __attribute__((ext_vector_type(8)));
typedef float   f32x4  __attribute__((ext_vector_type(4)));

#define NTOK 100352   // 32 * 56 * 56
#define QSCALE 0.17677669529663687f

// all-reduce within the 16-lane DPP row via row_ror (VALU-only, no LDS pipe)
#define DPP_ROR_F(x, n) __int_as_float(__builtin_amdgcn_update_dpp( \
    0, __float_as_int(x), 0x120 + (n), 0xf, 0xf, false))

// ---------------- merged fp32 -> bf16 transposes (weights) ----------------
__global__ __launch_bounds__(256)
void cvt_all(const float* __restrict__ qkv_w, const float* __restrict__ proj_w,
             const float* __restrict__ fc1_w, const float* __restrict__ fc2_w,
             bf16* __restrict__ wqkvT, bf16* __restrict__ wprojT,
             bf16* __restrict__ wfc1T, bf16* __restrict__ wfc2T)
{
  const int i = blockIdx.x * 256 + threadIdx.x;
  if (i < 196608) {
    const int k = i / 768, n = i % 768;
    wqkvT[n * 256 + k] = __float2bfloat16(qkv_w[i]);
  } else if (i < 262144) {
    const int j = i - 196608, k = j / 256, n = j % 256;
    wprojT[n * 256 + k] = __float2bfloat16(proj_w[j]);
  } else if (i < 524288) {
    const int j = i - 262144, k = j / 1024, n = j % 1024;
    wfc1T[n * 256 + k] = __float2bfloat16(fc1_w[j]);
  } else {
    const int j = i - 524288, k = j / 256, n = j % 256;
    wfc2T[n * 1024 + k] = __float2bfloat16(fc2_w[j]);
  }
}

// ---------------- pos-bias MLP + rel_bias table (1 block) ----------------
__device__ __forceinline__ void ln16_relu(float* cur, const float* g, const float* b) {
  float mu = 0.f;
#pragma unroll
  for (int j = 0; j < 16; ++j) mu += cur[j];
  mu *= (1.f / 16.f);
  float var = 0.f;
#pragma unroll
  for (int j = 0; j < 16; ++j) { float d = cur[j] - mu; var += d * d; }
  var *= (1.f / 16.f);
  const float r = rsqrtf(var + 1e-5f);
#pragma unroll
  for (int j = 0; j < 16; ++j) {
    float y = (cur[j] - mu) * r * g[j] + b[j];
    cur[j] = fmaxf(y, 0.f);
  }
}

__global__ __launch_bounds__(256)
void pos_kernel(const float* __restrict__ ppw, const float* __restrict__ ppb,
                const float* __restrict__ g1, const float* __restrict__ lb1,
                const float* __restrict__ w1, const float* __restrict__ b1,
                const float* __restrict__ g2, const float* __restrict__ lb2,
                const float* __restrict__ w2, const float* __restrict__ b2,
                const float* __restrict__ g3, const float* __restrict__ lb3,
                const float* __restrict__ w3, const float* __restrict__ b3,
                float* __restrict__ rel_bias)
{
  __shared__ float pos_s[169 * 8];
  const int t = threadIdx.x;
  if (t < 169) {
    float cur[16], nxt[16];
    const float bh = (float)(t / 13 - 6), bw = (float)(t % 13 - 6);
#pragma unroll
    for (int j = 0; j < 16; ++j)
      cur[j] = bh * ppw[j] + bw * ppw[16 + j] + ppb[j];
    ln16_relu(cur, g1, lb1);
    for (int j = 0; j < 16; ++j) nxt[j] = b1[j];
    for (int k = 0; k < 16; ++k) { float a = cur[k]; for (int j = 0; j < 16; ++j) nxt[j] += a * w1[k * 16 + j]; }
    for (int j = 0; j < 16; ++j) cur[j] = nxt[j];
    ln16_relu(cur, g2, lb2);
    for (int j = 0; j < 16; ++j) nxt[j] = b2[j];
    for (int k = 0; k < 16; ++k) { float a = cur[k]; for (int j = 0; j < 16; ++j) nxt[j] += a * w2[k * 16 + j]; }
    for (int j = 0; j < 16; ++j) cur[j] = nxt[j];
    ln16_relu(cur, g3, lb3);
    for (int h = 0; h < 8; ++h) {
      float s = b3[h];
      for (int k = 0; k < 16; ++k) s += cur[k] * w3[k * 8 + h];
      pos_s[t * 8 + h] = s;
    }
  }
  __syncthreads();
  for (int e = t; e < 8 * 2401; e += 256) {
    const int h = e / 2401, ij = e % 2401, i = ij / 49, j = ij % 49;
    const int dh = i / 7 - j / 7 + 6, dw = i % 7 - j % 7 + 6;
    rel_bias[e] = pos_s[(dh * 13 + dw) * 8 + h];
  }
}

// ---------------- LayerNorm over C=256: one wave per token ----------------
__global__ __launch_bounds__(256)
void ln_wave(const float* __restrict__ xin,
             const float* __restrict__ g, const float* __restrict__ b,
             bf16* __restrict__ out)
{
  const int tok = blockIdx.x * 4 + (threadIdx.x >> 6);
  const int lane = threadIdx.x & 63;
  const float4 xv = *reinterpret_cast<const float4*>(xin + (size_t)tok * 256 + lane * 4);
  float s = xv.x + xv.y + xv.z + xv.w;
#pragma unroll
  for (int off = 1; off < 64; off <<= 1) s += __shfl_xor(s, off, 64);
  const float mu = s * (1.f / 256.f);
  const float4 dx = make_float4(xv.x - mu, xv.y - mu, xv.z - mu, xv.w - mu);
  float v = dx.x * dx.x + dx.y * dx.y + dx.z * dx.z + dx.w * dx.w;
#pragma unroll
  for (int off = 1; off < 64; off <<= 1) v += __shfl_xor(v, off, 64);
  const float rstd = rsqrtf(v * (1.f / 256.f) + 1e-5f);
  const float4 gv = *reinterpret_cast<const float4*>(g + lane * 4);
  const float4 bv = *reinterpret_cast<const float4*>(b + lane * 4);
  bf16 o0 = __float2bfloat16(dx.x * rstd * gv.x + bv.x);
  bf16 o1 = __float2bfloat16(dx.y * rstd * gv.y + bv.y);
  bf16 o2 = __float2bfloat16(dx.z * rstd * gv.z + bv.z);
  bf16 o3 = __float2bfloat16(dx.w * rstd * gv.w + bv.w);
  ushort4 st = make_ushort4(*(u16*)&o0, *(u16*)&o1, *(u16*)&o2, *(u16*)&o3);
  *reinterpret_cast<ushort4*>(out + (size_t)tok * 256 + lane * 4) = st;
}

// ---------------- MFMA GEMM, stream-A: block owns 128 rows, loops n-tiles --
// C[M,N] = A[M,K] @ BT[N,K]^T + epilogue. A re-staged per n-tile (XCD-L2 hot).
// EPI 0: QKV -> scatter q/k (token-major slices) and V transposed [d][56]
// EPI 1: proj -> outF (fp32) = acc + bias + resF
// EPI 2: fc1  -> outB (bf16) = gelu_exact(acc + bias)
// EPI 5: fc2  -> outF (fp32) = resF + acc + bias
template<int EPI>
__global__ __launch_bounds__(256, 2)
void gemm_mfma(const bf16* __restrict__ A, const bf16* __restrict__ BT,
               const float* __restrict__ bias, const float* __restrict__ resF,
               float* __restrict__ outF, bf16* __restrict__ outB,
               bf16* __restrict__ outQ, bf16* __restrict__ outK, bf16* __restrict__ outV,
               const int M, const int N, const int K, const int nTiles)
{
  __shared__ __align__(16) u16 Alds[128 * 32];
  __shared__ __align__(16) u16 Blds[128 * 32];
  const int t = threadIdx.x;
  const int m0 = blockIdx.x << 7;
  const int wave = t >> 6, lane = t & 63;
  const int quad = lane >> 4, l15 = lane & 15;
  const int mw = (wave & 1) << 6, nw = (wave >> 1) << 6;

  const int sr = t >> 2, sc = (t & 3) << 3;
  const bf16* ag0 = A + (size_t)(m0 + sr) * K + sc;
  const bf16* ag1 = ag0 + (size_t)64 * K;
  char* alds0 = (char*)Alds + t * 16;
  char* alds1 = (char*)Alds + 4096 + t * 16;
  char* blds0 = (char*)Blds + t * 16;
  char* blds1 = (char*)Blds + 4096 + t * 16;

  for (int nt = 0; nt < nTiles; ++nt) {
    const int n0 = nt << 7;
    const bf16* bg0 = BT + (size_t)(n0 + sr) * K + sc;
    const bf16* bg1 = bg0 + (size_t)64 * K;

    f32x4 acc[4][4];
#pragma unroll
    for (int mi = 0; mi < 4; ++mi)
#pragma unroll
      for (int ni = 0; ni < 4; ++ni) acc[mi][ni] = (f32x4){0.f, 0.f, 0.f, 0.f};

    for (int kt = 0; kt < K; kt += 32) {
      __builtin_amdgcn_global_load_lds((const __attribute__((address_space(1))) void*)(ag0 + kt),
          (__attribute__((address_space(3))) void*)alds0, 16, 0, 0);
      __builtin_amdgcn_global_load_lds((const __attribute__((address_space(1))) void*)(ag1 + kt),
          (__attribute__((address_space(3))) void*)alds1, 16, 0, 0);
      __builtin_amdgcn_global_load_lds((const __attribute__((address_space(1))) void*)(bg0 + kt),
          (__attribute__((address_space(3))) void*)blds0, 16, 0, 0);
      __builtin_amdgcn_global_load_lds((const __attribute__((address_space(1))) void*)(bg1 + kt),
          (__attribute__((address_space(3))) void*)blds1, 16, 0, 0);
      __syncthreads();

      bf16x8 af[4], bfr[4];
#pragma unroll
      for (int mi = 0; mi < 4; ++mi)
        af[mi] = *(const bf16x8*)(Alds + (mw + mi * 16 + l15) * 32 + quad * 8);
#pragma unroll
      for (int ni = 0; ni < 4; ++ni)
        bfr[ni] = *(const bf16x8*)(Blds + (nw + ni * 16 + l15) * 32 + quad * 8);
#pragma unroll
      for (int mi = 0; mi < 4; ++mi)
#pragma unroll
        for (int ni = 0; ni < 4; ++ni)
          acc[mi][ni] = __builtin_amdgcn_mfma_f32_16x16x32_bf16(af[mi], bfr[ni], acc[mi][ni], 0, 0, 0);
      __syncthreads();
    }

#pragma unroll
    for (int mi = 0; mi < 4; ++mi) {
#pragma unroll
      for (int r = 0; r < 4; ++r) {
        const int m = m0 + mw + mi * 16 + quad * 4 + r;
        if (EPI == 0) {
          const int bb = m / 3136, l = m % 3136;
          const int hh = l / 56, ww = l % 56;
          const int win = bb * 64 + (hh / 7) * 8 + (ww / 7);
          const int p = (hh % 7) * 7 + (ww % 7);
          const size_t bidb = (size_t)win * 8;
#pragma unroll
          for (int ni = 0; ni < 4; ++ni) {
            const int n = n0 + nw + ni * 16 + l15;
            const float val = acc[mi][ni][r] + bias[n];
            const int which = n >> 8, head = (n >> 5) & 7, d = n & 31;
            if (which == 0)
              outQ[(bidb + head) * 1568 + p * 32 + d] = __float2bfloat16(val * QSCALE);
            else if (which == 1)
              outK[(bidb + head) * 1568 + p * 32 + d] = __float2bfloat16(val);
            else  // V transposed: [bid][d][56]
              outV[(bidb + head) * 1792 + d * 56 + p] = __float2bfloat16(val);
          }
        } else if (EPI == 1) {
#pragma unroll
          for (int ni = 0; ni < 4; ++ni) {
            const int n = n0 + nw + ni * 16 + l15;
            outF[(size_t)m * N + n] = acc[mi][ni][r] + bias[n] + resF[(size_t)m * N + n];
          }
        } else if (EPI == 2) {
#pragma unroll
          for (int ni = 0; ni < 4; ++ni) {
            const int n = n0 + nw + ni * 16 + l15;
            const float z = acc[mi][ni][r] + bias[n];
            const float ge = 0.5f * z * (1.f + erff(z * 0.7071067811865476f));
            outB[(size_t)m * N + n] = __float2bfloat16(ge);
          }
        } else {
#pragma unroll
          for (int ni = 0; ni < 4; ++ni) {
            const int n = n0 + nw + ni * 16 + l15;
            outF[(size_t)m * N + n] = resF[(size_t)m * N + n] + acc[mi][ni][r] + bias[n];
          }
        }
      }
    }
  }
}

// ---------------- MFMA attention v3: one wave per (window, head) ------------
// Q/K fragments and V B-fragments loaded directly from global (V pre-
// transposed [d][56] by the QKV epilogue). Softmax reductions via DPP
// row_ror (VALU-only). Only the P C->A layout round-trip uses LDS (9216 B).
__global__ __launch_bounds__(64)
void attn_mfma(const bf16* __restrict__ q, const bf16* __restrict__ k,
               const bf16* __restrict__ v, const float* __restrict__ rel_bias,
               bf16* __restrict__ out)
{
  __shared__ __align__(16) u16 Ps[64 * 72];
  const int bid = blockIdx.x;           // win*8 + head
  const int win = bid >> 3, head = bid & 7;
  const int lane = threadIdx.x;
  const int quad = lane >> 4, l15 = lane & 15;
  const size_t base = (size_t)bid * 1568;
  const bf16* vbase = v + (size_t)bid * 1792;

  // Q/K fragments: 16B loads, row clamped to stay in-slice
  bf16x8 qf[4], kf[4];
#pragma unroll
  for (int mi = 0; mi < 4; ++mi) {
    const int rr = mi * 16 + l15;
    const int rc = rr < 49 ? rr : 48;
    qf[mi] = *(const bf16x8*)(q + base + rc * 32 + quad * 8);
    kf[mi] = *(const bf16x8*)(k + base + rc * 32 + quad * 8);
  }
  // V B-fragments: vf[kt][ni] = VT[d=ni*16+l15][j=kt*32+quad*8 .. +7]
  // (j>=49 garbage annihilated by P zeros)
  bf16x8 vf[2][2];
#pragma unroll
  for (int kt = 0; kt < 2; ++kt)
#pragma unroll
    for (int ni = 0; ni < 2; ++ni)
      vf[kt][ni] = *(const bf16x8*)(vbase + (ni * 16 + l15) * 56 + kt * 32 + quad * 8);

  f32x4 S[4][4];
#pragma unroll
  for (int mi = 0; mi < 4; ++mi)
#pragma unroll
    for (int ni = 0; ni < 4; ++ni)
      S[mi][ni] = __builtin_amdgcn_mfma_f32_16x16x32_bf16(qf[mi], kf[ni],
                                                          (f32x4){0.f, 0.f, 0.f, 0.f}, 0, 0, 0);

  // bias + mask + row softmax; all-reduce over 16 lanes via DPP row_ror
  const float* rb = rel_bias + head * 2401;
#pragma unroll
  for (int mi = 0; mi < 4; ++mi) {
#pragma unroll
    for (int r = 0; r < 4; ++r) {
      const int m = mi * 16 + quad * 4 + r;
      const int mc = m < 49 ? m : 48;
      float sv[4];
#pragma unroll
      for (int ni = 0; ni < 4; ++ni) {
        const int n = ni * 16 + l15;
        sv[ni] = (n < 49) ? (S[mi][ni][r] + rb[mc * 49 + n]) : -3e38f;
      }
      float mx = fmaxf(fmaxf(sv[0], sv[1]), fmaxf(sv[2], sv[3]));
      mx = fmaxf(mx, DPP_ROR_F(mx, 8));
      mx = fmaxf(mx, DPP_ROR_F(mx, 4));
      mx = fmaxf(mx, DPP_ROR_F(mx, 2));
      mx = fmaxf(mx, DPP_ROR_F(mx, 1));
      float sum = 0.f;
#pragma unroll
      for (int ni = 0; ni < 4; ++ni) { sv[ni] = __expf(sv[ni] - mx); sum += sv[ni]; }
      sum += DPP_ROR_F(sum, 8);
      sum += DPP_ROR_F(sum, 4);
      sum += DPP_ROR_F(sum, 2);
      sum += DPP_ROR_F(sum, 1);
      const float inv = 1.f / sum;
#pragma unroll
      for (int ni = 0; ni < 4; ++ni) S[mi][ni][r] = sv[ni] * inv;
    }
  }

  // P -> LDS in A-operand layout [m][j], ld=72
#pragma unroll
  for (int mi = 0; mi < 4; ++mi)
#pragma unroll
    for (int r = 0; r < 4; ++r) {
      const int m = mi * 16 + quad * 4 + r;
#pragma unroll
      for (int ni = 0; ni < 4; ++ni) {
        const bf16 pb = __float2bfloat16(S[mi][ni][r]);
        Ps[m * 72 + ni * 16 + l15] = *(const u16*)&pb;
      }
    }
  __syncthreads();

  // O = P @ V
  f32x4 O[4][2];
#pragma unroll
  for (int mi = 0; mi < 4; ++mi)
#pragma unroll
    for (int ni = 0; ni < 2; ++ni) O[mi][ni] = (f32x4){0.f, 0.f, 0.f, 0.f};
#pragma unroll
  for (int kt = 0; kt < 2; ++kt) {
    bf16x8 pf[4];
#pragma unroll
    for (int mi = 0; mi < 4; ++mi)
      pf[mi] = *(const bf16x8*)(Ps + (mi * 16 + l15) * 72 + kt * 32 + quad * 8);
#pragma unroll
    for (int ni = 0; ni < 2; ++ni)
#pragma unroll
      for (int mi = 0; mi < 4; ++mi)
        O[mi][ni] = __builtin_amdgcn_mfma_f32_16x16x32_bf16(pf[mi], vf[kt][ni], O[mi][ni], 0, 0, 0);
  }

  // write out token-major [tok][256]
  const int b = win >> 6, wh = (win >> 3) & 7, wwd = win & 7;
#pragma unroll
  for (int mi = 0; mi < 4; ++mi) {
#pragma unroll
    for (int r = 0; r < 4; ++r) {
      const int m = mi * 16 + quad * 4 + r;
      if (m < 49) {
        const int r7 = m / 7, c7 = m % 7;
        const int tok = b * 3136 + (wh * 7 + r7) * 56 + (wwd * 7 + c7);
        bf16* op = out + (size_t)tok * 256 + head * 32;
#pragma unroll
        for (int ni = 0; ni < 2; ++ni)
          op[ni * 16 + l15] = __float2bfloat16(O[mi][ni][r]);
      }
    }
  }
}

// ---------------- launch ----------------
// Workspace (~215 MB):
//   [0,128KB) rel_bias; [128KB,2MB) bf16 transposed weights
//   R1 (REG): xn -> aout          R2,R3 (REG each): q,k -> Hc (MLP hidden)
//   RV (16384*3584 + 4KB): V transposed -> yn
//   fp32 residual xr lives in d_out (proj writes, LN2 reads, FC2 rmw).
extern "C" void kernel_launch(void* const* d_in, const int* in_sizes, int n_in,
                              void* d_out, int out_size, void* d_ws, size_t ws_size,
                              hipStream_t stream)
{
  const float* x      = (const float*)d_in[0];
  const float* n1g    = (const float*)d_in[1];
  const float* n1b    = (const float*)d_in[2];
  const float* qkv_w  = (const float*)d_in[3];
  const float* qkv_b  = (const float*)d_in[4];
  const float* proj_w = (const float*)d_in[5];
  const float* proj_b = (const float*)d_in[6];
  const float* pp_w   = (const float*)d_in[7];
  const float* pp_b   = (const float*)d_in[8];
  const float* p1g    = (const float*)d_in[9];
  const float* p1lb   = (const float*)d_in[10];
  const float* p1w    = (const float*)d_in[11];
  const float* p1b    = (const float*)d_in[12];
  const float* p2g    = (const float*)d_in[13];
  const float* p2lb   = (const float*)d_in[14];
  const float* p2w    = (const float*)d_in[15];
  const float* p2b    = (const float*)d_in[16];
  const float* p3g    = (const float*)d_in[17];
  const float* p3lb   = (const float*)d_in[18];
  const float* p3w    = (const float*)d_in[19];
  const float* p3b    = (const float*)d_in[20];
  const float* n2g    = (const float*)d_in[21];
  const float* n2b    = (const float*)d_in[22];
  const float* fc1_w  = (const float*)d_in[23];
  const float* fc1_b  = (const float*)d_in[24];
  const float* fc2_w  = (const float*)d_in[25];
  const float* fc2_b  = (const float*)d_in[26];

  const size_t REG = (size_t)NTOK * 256 * 2;        // 51,380,224
  const size_t VREG = (size_t)16384 * 3584 + 4096;  // 58,724,352
  char* ws = (char*)d_ws;
  float* rel_bias = (float*)ws;
  bf16* wqkvT = (bf16*)(ws + 131072);
  bf16* wprojT = wqkvT + 196608;
  bf16* wfc1T = wprojT + 65536;
  bf16* wfc2T = wfc1T + 262144;
  char* R1 = ws + (2 << 20);
  char* R2 = R1 + REG;
  char* R3 = R2 + REG;
  char* RV = R3 + REG;

  bf16*  xn   = (bf16*)R1;        // phase 1
  bf16*  qb   = (bf16*)R2;
  bf16*  kb   = (bf16*)R3;
  bf16*  vb   = (bf16*)RV;        // transposed V [bid][32][56]
  bf16*  aout = (bf16*)R1;        // phase 2 (xn dead)
  float* xr   = (float*)d_out;    // fp32 residual in output buffer
  bf16*  yn   = (bf16*)RV;        // phase 4 (v dead)
  bf16*  Hc   = (bf16*)R2;        // phase 5 (q,k dead) — spans R2+R3
  (void)VREG;

  cvt_all<<<3072, 256, 0, stream>>>(qkv_w, proj_w, fc1_w, fc2_w,
                                    wqkvT, wprojT, wfc1T, wfc2T);
  pos_kernel<<<1, 256, 0, stream>>>(pp_w, pp_b, p1g, p1lb, p1w, p1b,
                                    p2g, p2lb, p2w, p2b, p3g, p3lb, p3w, p3b, rel_bias);
  ln_wave<<<NTOK / 4, 256, 0, stream>>>(x, n1g, n1b, xn);
  gemm_mfma<0><<<NTOK / 128, 256, 0, stream>>>(xn, wqkvT, qkv_b, nullptr,
      nullptr, nullptr, qb, kb, vb, NTOK, 768, 256, 6);
  attn_mfma<<<16384, 64, 0, stream>>>(qb, kb, vb, rel_bias, aout);
  gemm_mfma<1><<<NTOK / 128, 256, 0, stream>>>(aout, wprojT, proj_b, x,
      xr, nullptr, nullptr, nullptr, nullptr, NTOK, 256, 256, 2);
  ln_wave<<<NTOK / 4, 256, 0, stream>>>(xr, n2g, n2b, yn);

  // MLP in 2 M-chunks of 50176 tokens (hidden chunk = R2+R3):
  const int MC = 50176;
  for (int c = 0; c < 2; ++c) {
    const size_t mb = (size_t)c * MC;
    gemm_mfma<2><<<MC / 128, 256, 0, stream>>>(yn + mb * 256, wfc1T,
        fc1_b, nullptr, nullptr, Hc, nullptr, nullptr, nullptr, MC, 1024, 256, 8);
    gemm_mfma<5><<<MC / 128, 256, 0, stream>>>(Hc, wfc2T,
        fc2_b, xr + mb * 256, xr + mb * 256, nullptr, nullptr, nullptr, nullptr,
        MC, 256, 1024, 2);
  }
}